// Round 2
// baseline (380.952 us; speedup 1.0000x reference)
//
#include <hip/hip_runtime.h>
#include <hip/hip_fp16.h>

// MSAAttention: x = e + PE; q,k,v = Linear(x); out = softmax(q k^T) v
// B=8 S=2048 H=512, fp32 in/out. Strategy: f16 MFMA for all GEMMs, fp32 softmax.
//
// Adaptive to ws_size (round-2 hardening: do NOT assume scratch >= 178 MiB):
//   Path A (ws >= ~178 MiB): S fp32 [8][2048][2048] materialized at once.
//   Path B (ws >= ~66 MiB):  per-batch 16 MiB S buffer, looped over B in stream order.
// Shared layout: q16/k16/vt f16 (16 MiB each) + w16 (1.5 MiB); x16 overlays the
// S region (dead before S is first written).

using half8   = __attribute__((ext_vector_type(8))) _Float16;
using half4v  = __attribute__((ext_vector_type(4))) _Float16;
using floatx4 = __attribute__((ext_vector_type(4))) float;

#define LDT 40  // LDS row stride in halves: 32 + 8 pad -> 80B stride, 16B aligned, 2-way-only bank alias

// ---- prep: x16 = f16(embeds + positional encoding) ----
__global__ __launch_bounds__(256) void prep_x_kernel(const float* __restrict__ e,
                                                     _Float16* __restrict__ x16) {
  int t = blockIdx.x * 256 + threadIdx.x;  // 2M threads, 4 elems each
  int idx = t * 4;
  int h = idx & 511;
  int s = (idx >> 9) & 2047;
  float4 ev = *(const float4*)(e + idx);
  const float ks = -9.210340371976184f / 256.0f;  // -ln(10000)/256 ; div[i]=exp(-i*ln1e4/256)
  float r[4] = {ev.x, ev.y, ev.z, ev.w};
#pragma unroll
  for (int j = 0; j < 4; j++) {
    int hh = h + j;
    int i = (hh < 256) ? hh : (hh - 256);
    float ang = (float)s * expf((float)i * ks);
    r[j] += (hh < 256) ? sinf(ang) : cosf(ang);
  }
  half4v o = {(_Float16)r[0], (_Float16)r[1], (_Float16)r[2], (_Float16)r[3]};
  *(half4v*)(x16 + idx) = o;
}

// ---- convert the three 512x512 weight matrices to f16 ----
__global__ __launch_bounds__(256) void cvt_w_kernel(const float* __restrict__ wq,
                                                    const float* __restrict__ wk,
                                                    const float* __restrict__ wv,
                                                    _Float16* __restrict__ oq,
                                                    _Float16* __restrict__ ok,
                                                    _Float16* __restrict__ ov) {
  int i = blockIdx.x * 256 + threadIdx.x;  // 262144 per matrix
  oq[i] = (_Float16)wq[i];
  ok[i] = (_Float16)wk[i];
  ov[i] = (_Float16)wv[i];
}

// ---- generic f16 MFMA GEMM: C[m][n] = sum_k A[m][k] * B[n][k] (+bias[n]) ----
// A [M,K] k-contiguous (lda), B [N,K] k-contiguous (ldb).
// 128x128 block tile, 4 waves in 2x2, each wave 64x64 via 4x4 frags of 16x16x32 MFMA.
// TRANS: store C[n][m] instead (used to produce V^T).
template <typename OutT, bool BIAS, bool TRANS>
__global__ __launch_bounds__(256) void gemm_tn(const _Float16* __restrict__ A,
                                               const _Float16* __restrict__ B,
                                               const float* __restrict__ bias,
                                               OutT* __restrict__ C,
                                               int lda, int ldb, int ldo, int K,
                                               long long sA, long long sB, long long sC) {
  __shared__ _Float16 Ash[128 * LDT];
  __shared__ _Float16 Bsh[128 * LDT];
  A += (long long)blockIdx.z * sA;
  B += (long long)blockIdx.z * sB;
  C += (long long)blockIdx.z * sC;
  const int m0 = blockIdx.y * 128, n0 = blockIdx.x * 128;
  const int tid = threadIdx.x;
  const int lane = tid & 63, wave = tid >> 6;
  const int wm = (wave >> 1) * 64, wn = (wave & 1) * 64;
  const int quad = lane >> 4, l16 = lane & 15;

  floatx4 acc[4][4] = {};

  // staging: thread t loads 32B (16 halves) of row sr at col sc
  const int sr = tid >> 1, sc = (tid & 1) * 16;
  const _Float16* Ag = A + (long long)(m0 + sr) * lda + sc;
  const _Float16* Bg = B + (long long)(n0 + sr) * ldb + sc;
  float4* AshW = (float4*)&Ash[sr * LDT + sc];
  float4* BshW = (float4*)&Bsh[sr * LDT + sc];

  for (int k0 = 0; k0 < K; k0 += 32) {
    float4 a0 = *(const float4*)(Ag + k0);
    float4 a1 = *(const float4*)(Ag + k0 + 8);
    float4 b0 = *(const float4*)(Bg + k0);
    float4 b1 = *(const float4*)(Bg + k0 + 8);
    __syncthreads();  // previous iter's LDS reads done
    AshW[0] = a0; AshW[1] = a1;
    BshW[0] = b0; BshW[1] = b1;
    __syncthreads();

    half8 af[4], bf[4];
#pragma unroll
    for (int i = 0; i < 4; i++) {
      // A-operand layout: frag[j] = X[row = lane&15][k = quad*8 + j]
      af[i] = *(const half8*)&Ash[(wm + 16 * i + l16) * LDT + quad * 8];
      bf[i] = *(const half8*)&Bsh[(wn + 16 * i + l16) * LDT + quad * 8];
    }
#pragma unroll
    for (int mi = 0; mi < 4; mi++)
#pragma unroll
      for (int ni = 0; ni < 4; ni++)
        acc[mi][ni] = __builtin_amdgcn_mfma_f32_16x16x32_f16(af[mi], bf[ni], acc[mi][ni], 0, 0, 0);
  }

  // C/D layout (m89-verified): row(m) = quad*4 + reg, col(n) = lane&15
#pragma unroll
  for (int ni = 0; ni < 4; ni++) {
    const int n = n0 + wn + 16 * ni + l16;
    const float bv = BIAS ? bias[n] : 0.0f;
#pragma unroll
    for (int mi = 0; mi < 4; mi++) {
      const int mg = m0 + wm + 16 * mi + quad * 4;
#pragma unroll
      for (int rr = 0; rr < 4; rr++) {
        float v = acc[mi][ni][rr] + bv;
        if (TRANS)
          C[(long long)n * ldo + (mg + rr)] = (OutT)v;
        else
          C[(long long)(mg + rr) * ldo + n] = (OutT)v;
      }
    }
  }
}

// ---- softmax over rows of S (fp32, 2048 wide), writing P as f16 in place ----
// One wave per row: shuffle-only reductions, no LDS/barriers.
// In-place safety: every store's data depends on sum (all of the wave's loads),
// so all loads complete before any store issues. P row stride = 4096 halves.
__global__ __launch_bounds__(256) void softmax_kernel(float* __restrict__ S) {
  const int lane = threadIdx.x & 63;
  const int wave = threadIdx.x >> 6;
  const long long row = (long long)blockIdx.x * 4 + wave;
  float* srow = S + row * 2048;
  const float4* p4 = (const float4*)srow;
  float v[32];
  float mx = -3.4e38f;
#pragma unroll
  for (int pass = 0; pass < 8; pass++) {
    float4 f = p4[pass * 64 + lane];
    v[pass * 4 + 0] = f.x; v[pass * 4 + 1] = f.y;
    v[pass * 4 + 2] = f.z; v[pass * 4 + 3] = f.w;
    mx = fmaxf(mx, fmaxf(fmaxf(f.x, f.y), fmaxf(f.z, f.w)));
  }
#pragma unroll
  for (int o = 32; o > 0; o >>= 1) mx = fmaxf(mx, __shfl_xor(mx, o));
  float sum = 0.0f;
#pragma unroll
  for (int j = 0; j < 32; j++) {
    v[j] = __expf(v[j] - mx);
    sum += v[j];
  }
#pragma unroll
  for (int o = 32; o > 0; o >>= 1) sum += __shfl_xor(sum, o);
  const float inv = 1.0f / sum;
  _Float16* prow = (_Float16*)srow;  // overlay: halves in first 4KB of the 8KB row
#pragma unroll
  for (int pass = 0; pass < 8; pass++) {
    int i4 = pass * 64 + lane;
    half4v o4 = {(_Float16)(v[pass * 4 + 0] * inv), (_Float16)(v[pass * 4 + 1] * inv),
                 (_Float16)(v[pass * 4 + 2] * inv), (_Float16)(v[pass * 4 + 3] * inv)};
    *(half4v*)(prow + 4 * i4) = o4;
  }
}

extern "C" void kernel_launch(void* const* d_in, const int* in_sizes, int n_in,
                              void* d_out, int out_size, void* d_ws, size_t ws_size,
                              hipStream_t stream) {
  const float* e  = (const float*)d_in[0];
  const float* Wq = (const float*)d_in[1];
  const float* bq = (const float*)d_in[2];
  const float* Wk = (const float*)d_in[3];
  const float* bk = (const float*)d_in[4];
  const float* Wv = (const float*)d_in[5];
  const float* bv = (const float*)d_in[6];
  float* out = (float*)d_out;
  char* ws = (char*)d_ws;

  const long long MiB = 1024LL * 1024LL;
  // Path A needs: 128 MiB S + 48 MiB qkv + 1.5 MiB weights
  // Path B needs:  16 MiB S + 48 MiB qkv + 1.5 MiB weights
  const bool big = ws_size >= (size_t)(128 * MiB + 48 * MiB + 2 * MiB);
  const long long Sbytes = big ? 128 * MiB : 16 * MiB;

  float*    S    = (float*)ws;            // per-path size; x16 overlays its head
  _Float16* x16  = (_Float16*)ws;         // 16 MiB, dead before S is first written
  _Float16* q16  = (_Float16*)(ws + Sbytes);
  _Float16* k16  = (_Float16*)(ws + Sbytes + 16 * MiB);
  _Float16* vt   = (_Float16*)(ws + Sbytes + 32 * MiB);
  _Float16* wq16 = (_Float16*)(ws + Sbytes + 48 * MiB);
  _Float16* wk16 = wq16 + 262144;
  _Float16* wv16 = wq16 + 2 * 262144;

  prep_x_kernel<<<8192, 256, 0, stream>>>(e, x16);
  cvt_w_kernel<<<1024, 256, 0, stream>>>(Wq, Wk, Wv, wq16, wk16, wv16);

  // QKV projections: M=16384 N=512 K=512; nn.Linear => B operand = W[d][h], k-contiguous
  dim3 gq(4, 128, 1);
  gemm_tn<_Float16, true, false><<<gq, 256, 0, stream>>>(x16, wq16, bq, q16, 512, 512, 512, 512, 0, 0, 0);
  gemm_tn<_Float16, true, false><<<gq, 256, 0, stream>>>(x16, wk16, bk, k16, 512, 512, 512, 512, 0, 0, 0);
  gemm_tn<_Float16, true, true ><<<gq, 256, 0, stream>>>(x16, wv16, bv, vt, 512, 512, 16384, 512, 0, 0, 0);

  if (big) {
    // S = q k^T batched: M=N=2048 K=512, fp32 out
    dim3 gs(16, 16, 8);
    gemm_tn<float, false, false><<<gs, 256, 0, stream>>>(q16, k16, nullptr, S,
                                                         512, 512, 2048, 512,
                                                         1048576LL, 1048576LL, 4194304LL);
    softmax_kernel<<<4096, 256, 0, stream>>>(S);
    // out = P v: A=(half)S lda=4096, B=vt with per-batch col offset 2048, K=2048
    dim3 gp(4, 16, 8);
    gemm_tn<float, false, false><<<gp, 256, 0, stream>>>((const _Float16*)S, vt, nullptr, out,
                                                         4096, 16384, 512, 2048,
                                                         8388608LL, 2048LL, 1048576LL);
  } else {
    // Per-batch loop over a single 16 MiB S buffer (stream order serializes reuse)
    for (int b = 0; b < 8; b++) {
      dim3 gs(16, 16, 1);
      gemm_tn<float, false, false><<<gs, 256, 0, stream>>>(q16 + (long long)b * 1048576,
                                                           k16 + (long long)b * 1048576,
                                                           nullptr, S,
                                                           512, 512, 2048, 512, 0, 0, 0);
      softmax_kernel<<<512, 256, 0, stream>>>(S);
      dim3 gp(4, 16, 1);
      gemm_tn<float, false, false><<<gp, 256, 0, stream>>>((const _Float16*)S,
                                                           vt + (long long)b * 2048,
                                                           nullptr,
                                                           out + (long long)b * 1048576,
                                                           4096, 16384, 512, 2048, 0, 0, 0);
    }
  }
}

// Round 3
// 295.426 us; speedup vs baseline: 1.2895x; 1.2895x over previous
//
#include <hip/hip_runtime.h>
#include <hip/hip_fp16.h>

// MSAAttention: x = e + PE; q,k,v = Linear(x); out = softmax(q k^T) v
// B=8 S=2048 H=512, fp32 in/out. f16 MFMA GEMMs + fp32 softmax.
//
// Round 3: m97-style global_load_lds(width=16) staging (unpadded 64B LDS rows),
// fused QKV (N=1536, one launch), PV retiled to BM=64 (grid 1024 = 4 blk/CU)
// with XCD-aware 1D block decode so the 4 x-blocks sharing a P row-tile land
// on the same XCD (L2 sharing of the A operand).

using half8   = __attribute__((ext_vector_type(8))) _Float16;
using half4v  = __attribute__((ext_vector_type(4))) _Float16;
using floatx4 = __attribute__((ext_vector_type(4))) float;

#define BK 32  // halves per K chunk -> 64 B LDS row, unpadded (global_load_lds layout)

__device__ __forceinline__ void g2l16(const void* g, void* l) {
  // async global->LDS DMA, 16 B per lane; LDS dest = wave-uniform base + lane*16
  __builtin_amdgcn_global_load_lds((const __attribute__((address_space(1))) void*)g,
                                   (__attribute__((address_space(3))) void*)l, 16, 0, 0);
}

// ---- prep: x16 = f16(embeds + positional encoding) ----
__global__ __launch_bounds__(256) void prep_x_kernel(const float* __restrict__ e,
                                                     _Float16* __restrict__ x16) {
  int t = blockIdx.x * 256 + threadIdx.x;  // 2M threads, 4 elems each
  int idx = t * 4;
  int h = idx & 511;
  int s = (idx >> 9) & 2047;
  float4 ev = *(const float4*)(e + idx);
  const float ks = -9.210340371976184f / 256.0f;  // -ln(10000)/256
  float r[4] = {ev.x, ev.y, ev.z, ev.w};
#pragma unroll
  for (int j = 0; j < 4; j++) {
    int hh = h + j;
    int i = (hh < 256) ? hh : (hh - 256);
    float ang = (float)s * expf((float)i * ks);
    r[j] += (hh < 256) ? sinf(ang) : cosf(ang);
  }
  half4v o = {(_Float16)r[0], (_Float16)r[1], (_Float16)r[2], (_Float16)r[3]};
  *(half4v*)(x16 + idx) = o;
}

// ---- build concatenated f16 weights [1536][512] + fp32 bias [1536] ----
__global__ __launch_bounds__(256) void cvt_w_kernel(const float* __restrict__ wq,
                                                    const float* __restrict__ wk,
                                                    const float* __restrict__ wv,
                                                    const float* __restrict__ bq,
                                                    const float* __restrict__ bk,
                                                    const float* __restrict__ bv,
                                                    _Float16* __restrict__ wcat,
                                                    float* __restrict__ bcat) {
  int i = blockIdx.x * 256 + threadIdx.x;  // 786432
  int m = i & 262143;
  const float* s = (i < 262144) ? wq : (i < 524288) ? wk : wv;
  wcat[i] = (_Float16)s[m];
  if (i < 512) bcat[i] = bq[i];
  else if (i < 1024) bcat[i] = bk[i - 512];
  else if (i < 1536) bcat[i] = bv[i - 1024];
}

// ---- f16 MFMA GEMM: C[m][n] = sum_k A[m][k]*B[n][k] ----
// A [M,K] lda, B [N,K] ldb, both k-contiguous. Tile BM x 128, BK=32, 4 waves
// (2x2), wave tile (BM/2) x 64 via 16x16x32 frags. Staging via global_load_lds.
// MODE 0: plain store OutT. MODE 1: QKV epilogue (bias + route q/k plain, v
// transposed). MODE 2: 1D grid with XCD-aware decode (PV).
template <int BM, typename OutT, int MODE>
__global__ __launch_bounds__(256) void gemm2(const _Float16* __restrict__ A,
                                             const _Float16* __restrict__ B,
                                             const float* __restrict__ bias,
                                             OutT* __restrict__ C,
                                             int lda, int ldb, int ldo, int K,
                                             long long sA, long long sB, long long sC,
                                             _Float16* __restrict__ oq,
                                             _Float16* __restrict__ ok,
                                             _Float16* __restrict__ ov,
                                             int GY) {
  __shared__ _Float16 Ash[BM * BK];
  __shared__ _Float16 Bsh[128 * BK];
  int bx, by, bz;
  if constexpr (MODE == 2) {
    // decode so the 4 x-blocks of one (y,z) group share i%8 (same XCD)
    int i = blockIdx.x;
    int c = i & 7, j = i >> 3;
    bx = j & 3;
    int t = j >> 2;
    int g = c * (gridDim.x >> 5) + t;
    by = g % GY;
    bz = g / GY;
  } else {
    bx = blockIdx.x; by = blockIdx.y; bz = blockIdx.z;
  }
  A += (long long)bz * sA;
  B += (long long)bz * sB;
  C += (long long)bz * sC;
  const int m0 = by * BM, n0 = bx * 128;
  const int tid = threadIdx.x;
  const int lane = tid & 63, wave = tid >> 6;
  constexpr int WM = BM / 2;
  constexpr int MI = WM / 16;
  constexpr int AIt = BM / 64;  // A staging issues per wave
  const int wm = (wave >> 1) * WM, wn = (wave & 1) * 64;
  const int quad = lane >> 4, l16 = lane & 15;
  const int lrow = lane >> 2;        // row within a 16-row staging issue
  const int lcol = (lane & 3) * 8;   // half offset within the 32-half row

  floatx4 acc[MI][4] = {};

  for (int k0 = 0; k0 < K; k0 += BK) {
    __syncthreads();  // prior iteration's ds_reads complete before DMA overwrites
#pragma unroll
    for (int t = 0; t < AIt; t++) {
      int is = wave * AIt + t;
      g2l16(A + (long long)(m0 + is * 16 + lrow) * lda + k0 + lcol, &Ash[is * 16 * BK]);
    }
#pragma unroll
    for (int t = 0; t < 2; t++) {
      int is = wave * 2 + t;
      g2l16(B + (long long)(n0 + is * 16 + lrow) * ldb + k0 + lcol, &Bsh[is * 16 * BK]);
    }
    __syncthreads();  // compiler drains vmcnt before the barrier -> DMA complete

    half8 af[MI], bf[4];
#pragma unroll
    for (int i = 0; i < MI; i++)
      af[i] = *(const half8*)&Ash[(wm + 16 * i + l16) * BK + quad * 8];
#pragma unroll
    for (int i = 0; i < 4; i++)
      bf[i] = *(const half8*)&Bsh[(wn + 16 * i + l16) * BK + quad * 8];
#pragma unroll
    for (int mi = 0; mi < MI; mi++)
#pragma unroll
      for (int ni = 0; ni < 4; ni++)
        acc[mi][ni] = __builtin_amdgcn_mfma_f32_16x16x32_f16(af[mi], bf[ni], acc[mi][ni], 0, 0, 0);
  }

  // C/D layout (m89-verified): row(m) = quad*4 + reg, col(n) = lane&15
#pragma unroll
  for (int ni = 0; ni < 4; ni++) {
    const int n = n0 + wn + 16 * ni + l16;
    float bv = 0.0f;
    if constexpr (MODE == 1) bv = bias[n];
#pragma unroll
    for (int mi = 0; mi < MI; mi++) {
      const int mg = m0 + wm + 16 * mi + quad * 4;
#pragma unroll
      for (int rr = 0; rr < 4; rr++) {
        float v = acc[mi][ni][rr] + bv;
        if constexpr (MODE == 1) {
          int m = mg + rr;
          if (n < 512) oq[m * 512 + n] = (_Float16)v;
          else if (n < 1024) ok[m * 512 + (n - 512)] = (_Float16)v;
          else ov[(n - 1024) * 16384 + m] = (_Float16)v;  // V^T
        } else {
          C[(long long)(mg + rr) * ldo + n] = (OutT)v;
        }
      }
    }
  }
}

// ---- softmax over fp32 rows of S (2048 wide), P f16 written in place ----
// One wave per row, shuffle-only reductions. Stores depend on sum (all loads),
// so in-place overlay is safe. P row stride = 4096 halves.
__global__ __launch_bounds__(256) void softmax_kernel(float* __restrict__ S) {
  const int lane = threadIdx.x & 63;
  const int wave = threadIdx.x >> 6;
  const long long row = (long long)blockIdx.x * 4 + wave;
  float* srow = S + row * 2048;
  const float4* p4 = (const float4*)srow;
  float v[32];
  float mx = -3.4e38f;
#pragma unroll
  for (int pass = 0; pass < 8; pass++) {
    float4 f = p4[pass * 64 + lane];
    v[pass * 4 + 0] = f.x; v[pass * 4 + 1] = f.y;
    v[pass * 4 + 2] = f.z; v[pass * 4 + 3] = f.w;
    mx = fmaxf(mx, fmaxf(fmaxf(f.x, f.y), fmaxf(f.z, f.w)));
  }
#pragma unroll
  for (int o = 32; o > 0; o >>= 1) mx = fmaxf(mx, __shfl_xor(mx, o));
  float sum = 0.0f;
#pragma unroll
  for (int j = 0; j < 32; j++) {
    v[j] = __expf(v[j] - mx);
    sum += v[j];
  }
#pragma unroll
  for (int o = 32; o > 0; o >>= 1) sum += __shfl_xor(sum, o);
  const float inv = 1.0f / sum;
  _Float16* prow = (_Float16*)srow;
#pragma unroll
  for (int pass = 0; pass < 8; pass++) {
    int i4 = pass * 64 + lane;
    half4v o4 = {(_Float16)(v[pass * 4 + 0] * inv), (_Float16)(v[pass * 4 + 1] * inv),
                 (_Float16)(v[pass * 4 + 2] * inv), (_Float16)(v[pass * 4 + 3] * inv)};
    *(half4v*)(prow + 4 * i4) = o4;
  }
}

extern "C" void kernel_launch(void* const* d_in, const int* in_sizes, int n_in,
                              void* d_out, int out_size, void* d_ws, size_t ws_size,
                              hipStream_t stream) {
  const float* e  = (const float*)d_in[0];
  const float* Wq = (const float*)d_in[1];
  const float* bq = (const float*)d_in[2];
  const float* Wk = (const float*)d_in[3];
  const float* bk = (const float*)d_in[4];
  const float* Wv = (const float*)d_in[5];
  const float* bv = (const float*)d_in[6];
  float* out = (float*)d_out;
  char* ws = (char*)d_ws;

  const long long MiB = 1024LL * 1024LL;
  const bool big = ws_size >= (size_t)(178 * MiB);
  const long long Sbytes = big ? 128 * MiB : 16 * MiB;

  float*    S    = (float*)ws;
  _Float16* x16  = (_Float16*)ws;  // overlays S head; dead before S written
  _Float16* q16  = (_Float16*)(ws + Sbytes);
  _Float16* k16  = (_Float16*)(ws + Sbytes + 16 * MiB);
  _Float16* vt   = (_Float16*)(ws + Sbytes + 32 * MiB);
  _Float16* wcat = (_Float16*)(ws + Sbytes + 48 * MiB);   // 1.5 MiB
  float*    bcat = (float*)(ws + Sbytes + 48 * MiB + 1536 * 1024);

  prep_x_kernel<<<8192, 256, 0, stream>>>(e, x16);
  cvt_w_kernel<<<3072, 256, 0, stream>>>(Wq, Wk, Wv, bq, bk, bv, wcat, bcat);

  // fused QKV: M=16384 N=1536 K=512; epilogue routes q/k plain, v transposed
  gemm2<128, _Float16, 1><<<dim3(12, 128, 1), 256, 0, stream>>>(
      x16, wcat, bcat, (_Float16*)nullptr, 512, 512, 0, 512, 0, 0, 0, q16, k16, vt, 0);

  if (big) {
    // S = q k^T batched: M=N=2048 K=512 fp32
    gemm2<128, float, 0><<<dim3(16, 16, 8), 256, 0, stream>>>(
        q16, k16, nullptr, S, 512, 512, 2048, 512,
        1048576LL, 1048576LL, 4194304LL, nullptr, nullptr, nullptr, 0);
    softmax_kernel<<<4096, 256, 0, stream>>>(S);
    // out = P v: BM=64, 1D grid 1024 with XCD decode; GY = 2048/64 = 32
    gemm2<64, float, 2><<<dim3(1024, 1, 1), 256, 0, stream>>>(
        (const _Float16*)S, vt, nullptr, out, 4096, 16384, 512, 2048,
        8388608LL, 2048LL, 1048576LL, nullptr, nullptr, nullptr, 32);
  } else {
    for (int b = 0; b < 8; b++) {
      gemm2<128, float, 0><<<dim3(16, 16, 1), 256, 0, stream>>>(
          q16 + (long long)b * 1048576, k16 + (long long)b * 1048576, nullptr, S,
          512, 512, 2048, 512, 0, 0, 0, nullptr, nullptr, nullptr, 0);
      softmax_kernel<<<512, 256, 0, stream>>>(S);
      gemm2<64, float, 2><<<dim3(128, 1, 1), 256, 0, stream>>>(
          (const _Float16*)S, vt + (long long)b * 2048, nullptr,
          out + (long long)b * 1048576, 4096, 16384, 512, 2048,
          0, 0, 0, nullptr, nullptr, nullptr, 32);
    }
  }
}

// Round 4
// 278.656 us; speedup vs baseline: 1.3671x; 1.0602x over previous
//
#include <hip/hip_runtime.h>
#include <hip/hip_fp16.h>

// MSAAttention: x = e + PE; q,k,v = Linear(x); out = softmax(q k^T) v
// B=8 S=2048 H=512, fp32 in/out. f16 MFMA GEMMs + fp32-math softmax.
//
// Round 4: S/P stored f16 (halves intermediate HBM traffic), BK=64 K-loop
// (half the barriers, 32 MFMA per stage per wave) with XOR-swizzled DMA
// staging to keep LDS b128 reads at the 8-clk minimum, fast-intrinsic prep.

using half8   = __attribute__((ext_vector_type(8))) _Float16;
using half4v  = __attribute__((ext_vector_type(4))) _Float16;
using floatx4 = __attribute__((ext_vector_type(4))) float;

#define BKH 64  // halves per K chunk -> 128 B LDS rows

__device__ __forceinline__ void g2l16(const void* g, void* l) {
  // async global->LDS DMA, 16 B/lane; LDS dest = wave-uniform base + lane*16
  __builtin_amdgcn_global_load_lds((const __attribute__((address_space(1))) void*)g,
                                   (__attribute__((address_space(3))) void*)l, 16, 0, 0);
}

// ---- prep: x16 = f16(embeds + positional encoding) ----
__global__ __launch_bounds__(256) void prep_x_kernel(const float* __restrict__ e,
                                                     _Float16* __restrict__ x16) {
  int t = blockIdx.x * 256 + threadIdx.x;  // 2M threads, 4 elems each
  int idx = t * 4;
  int h = idx & 511;
  int s = (idx >> 9) & 2047;
  float4 ev = *(const float4*)(e + idx);
  const float ks = -9.210340371976184f / 256.0f;  // -ln(10000)/256
  float r[4] = {ev.x, ev.y, ev.z, ev.w};
#pragma unroll
  for (int j = 0; j < 4; j++) {
    int hh = h + j;
    int i = (hh < 256) ? hh : (hh - 256);
    float ang = (float)s * __expf((float)i * ks);
    r[j] += (hh < 256) ? __sinf(ang) : __cosf(ang);
  }
  half4v o = {(_Float16)r[0], (_Float16)r[1], (_Float16)r[2], (_Float16)r[3]};
  *(half4v*)(x16 + idx) = o;
}

// ---- build concatenated f16 weights [1536][512] + fp32 bias [1536] ----
__global__ __launch_bounds__(256) void cvt_w_kernel(const float* __restrict__ wq,
                                                    const float* __restrict__ wk,
                                                    const float* __restrict__ wv,
                                                    const float* __restrict__ bq,
                                                    const float* __restrict__ bk,
                                                    const float* __restrict__ bv,
                                                    _Float16* __restrict__ wcat,
                                                    float* __restrict__ bcat) {
  int i = blockIdx.x * 256 + threadIdx.x;  // 786432
  int m = i & 262143;
  const float* s = (i < 262144) ? wq : (i < 524288) ? wk : wv;
  wcat[i] = (_Float16)s[m];
  if (i < 512) bcat[i] = bq[i];
  else if (i < 1024) bcat[i] = bk[i - 512];
  else if (i < 1536) bcat[i] = bv[i - 1024];
}

// ---- f16 MFMA GEMM: C[m][n] = sum_k A[m][k]*B[n][k] ----
// A [M,K] lda, B [N,K] ldb, k-contiguous. Tile BM x 128, BK=64, 4 waves (2x2),
// wave tile (BM/2) x 64 via 16x16x32 frags, 2 k-steps per staged chunk.
// Staging via global_load_lds; odd LDS rows store the two 32-half k-chunks
// swapped (XOR swizzle at the DMA *source* address) so the b128 fragment
// reads hit 8 lanes per 4-bank group (the wave64 minimum) instead of 16.
// MODE 0: plain store OutT. MODE 1: QKV epilogue (bias; q/k plain, v transposed).
// MODE 2: 1D grid, XCD-aware decode (PV).
template <int BM, typename OutT, int MODE>
__global__ __launch_bounds__(256) void gemm3(const _Float16* __restrict__ A,
                                             const _Float16* __restrict__ B,
                                             const float* __restrict__ bias,
                                             OutT* __restrict__ C,
                                             int lda, int ldb, int ldo, int K,
                                             long long sA, long long sB, long long sC,
                                             _Float16* __restrict__ oq,
                                             _Float16* __restrict__ ok,
                                             _Float16* __restrict__ ov,
                                             int GY) {
  __shared__ _Float16 Ash[BM * BKH];
  __shared__ _Float16 Bsh[128 * BKH];
  int bx, by, bz;
  if constexpr (MODE == 2) {
    // the 4 x-blocks of one (y,z) group share i%8 (same XCD) for A-operand L2 reuse
    int i = blockIdx.x;
    int c = i & 7, j = i >> 3;
    bx = j & 3;
    int t = j >> 2;
    int g = c * (gridDim.x >> 5) + t;
    by = g % GY;
    bz = g / GY;
  } else {
    bx = blockIdx.x; by = blockIdx.y; bz = blockIdx.z;
  }
  A += (long long)bz * sA;
  B += (long long)bz * sB;
  C += (long long)bz * sC;
  const int m0 = by * BM, n0 = bx * 128;
  const int tid = threadIdx.x;
  const int lane = tid & 63, wave = tid >> 6;
  constexpr int WM = BM / 2;
  constexpr int MI = WM / 16;
  constexpr int AIt = BM / 32;  // A staging issues per wave (8 rows / issue)
  const int wm = (wave >> 1) * WM, wn = (wave & 1) * 64;
  const int quad = lane >> 4, l16 = lane & 15;
  const int lrow = lane >> 3;                               // row within an 8-row issue
  const int lcol = ((lane & 7) * 8) ^ ((lrow & 1) * 32);    // swizzled source col (halves)

  floatx4 acc[MI][4] = {};

  for (int k0 = 0; k0 < K; k0 += BKH) {
    __syncthreads();  // prior iteration's ds_reads complete before DMA overwrites
#pragma unroll
    for (int t = 0; t < AIt; t++) {
      int is = wave * AIt + t;
      g2l16(A + (long long)(m0 + is * 8 + lrow) * lda + k0 + lcol, &Ash[is * 8 * BKH]);
    }
#pragma unroll
    for (int t = 0; t < 4; t++) {
      int is = wave * 4 + t;
      g2l16(B + (long long)(n0 + is * 8 + lrow) * ldb + k0 + lcol, &Bsh[is * 8 * BKH]);
    }
    __syncthreads();  // compiler drains vmcnt before barrier -> DMA complete

    const int sw = (l16 & 1) * 32;  // undo the per-row-parity chunk swap
#pragma unroll
    for (int kk = 0; kk < 2; kk++) {
      const int coff = (kk * 32) ^ sw;
      half8 af[MI], bf[4];
#pragma unroll
      for (int i = 0; i < MI; i++)
        af[i] = *(const half8*)&Ash[(wm + 16 * i + l16) * BKH + coff + quad * 8];
#pragma unroll
      for (int i = 0; i < 4; i++)
        bf[i] = *(const half8*)&Bsh[(wn + 16 * i + l16) * BKH + coff + quad * 8];
#pragma unroll
      for (int mi = 0; mi < MI; mi++)
#pragma unroll
        for (int ni = 0; ni < 4; ni++)
          acc[mi][ni] = __builtin_amdgcn_mfma_f32_16x16x32_f16(af[mi], bf[ni], acc[mi][ni], 0, 0, 0);
    }
  }

  // C/D layout (m89-verified): row(m) = quad*4 + reg, col(n) = lane&15
#pragma unroll
  for (int ni = 0; ni < 4; ni++) {
    const int n = n0 + wn + 16 * ni + l16;
    float bv = 0.0f;
    if constexpr (MODE == 1) bv = bias[n];
#pragma unroll
    for (int mi = 0; mi < MI; mi++) {
      const int mg = m0 + wm + 16 * mi + quad * 4;
#pragma unroll
      for (int rr = 0; rr < 4; rr++) {
        float v = acc[mi][ni][rr] + bv;
        if constexpr (MODE == 1) {
          int m = mg + rr;
          if (n < 512) oq[m * 512 + n] = (_Float16)v;
          else if (n < 1024) ok[m * 512 + (n - 512)] = (_Float16)v;
          else ov[(n - 1024) * 16384 + m] = (_Float16)v;  // V^T
        } else {
          C[(long long)(mg + rr) * ldo + n] = (OutT)v;
        }
      }
    }
  }
}

// ---- softmax over f16 rows of S (2048 wide), fp32 math, f16 in place ----
// One wave per row, shuffle-only reductions. All stores depend on sum (every
// load), so the in-place update is safe.
__global__ __launch_bounds__(256) void softmax_kernel(_Float16* __restrict__ S) {
  const int lane = threadIdx.x & 63;
  const int wave = threadIdx.x >> 6;
  const long long row = (long long)blockIdx.x * 4 + wave;
  _Float16* srow = S + row * 2048;
  float v[32];
  float mx = -3.4e38f;
#pragma unroll
  for (int pass = 0; pass < 4; pass++) {
    half8 f = *(const half8*)(srow + (pass * 64 + lane) * 8);
#pragma unroll
    for (int j = 0; j < 8; j++) {
      float x = (float)f[j];
      v[pass * 8 + j] = x;
      mx = fmaxf(mx, x);
    }
  }
#pragma unroll
  for (int o = 32; o > 0; o >>= 1) mx = fmaxf(mx, __shfl_xor(mx, o));
  float sum = 0.0f;
#pragma unroll
  for (int j = 0; j < 32; j++) {
    v[j] = __expf(v[j] - mx);
    sum += v[j];
  }
#pragma unroll
  for (int o = 32; o > 0; o >>= 1) sum += __shfl_xor(sum, o);
  const float inv = 1.0f / sum;
#pragma unroll
  for (int pass = 0; pass < 4; pass++) {
    half8 o8;
#pragma unroll
    for (int j = 0; j < 8; j++) o8[j] = (_Float16)(v[pass * 8 + j] * inv);
    *(half8*)(srow + (pass * 64 + lane) * 8) = o8;
  }
}

extern "C" void kernel_launch(void* const* d_in, const int* in_sizes, int n_in,
                              void* d_out, int out_size, void* d_ws, size_t ws_size,
                              hipStream_t stream) {
  const float* e  = (const float*)d_in[0];
  const float* Wq = (const float*)d_in[1];
  const float* bq = (const float*)d_in[2];
  const float* Wk = (const float*)d_in[3];
  const float* bk = (const float*)d_in[4];
  const float* Wv = (const float*)d_in[5];
  const float* bv = (const float*)d_in[6];
  float* out = (float*)d_out;
  char* ws = (char*)d_ws;

  const long long MiB = 1024LL * 1024LL;
  // big: S f16 [8][2048][2048] = 64 MiB all at once; small: per-batch 8 MiB
  const bool big = ws_size >= (size_t)(115 * MiB);
  const long long base = big ? 64 * MiB : 16 * MiB;  // x16 needs 16 MiB at head

  _Float16* S    = (_Float16*)ws;
  _Float16* x16  = (_Float16*)ws;  // overlays S head; dead before S written
  _Float16* q16  = (_Float16*)(ws + base);
  _Float16* k16  = (_Float16*)(ws + base + 16 * MiB);
  _Float16* vt   = (_Float16*)(ws + base + 32 * MiB);
  _Float16* wcat = (_Float16*)(ws + base + 48 * MiB);   // 1.5 MiB
  float*    bcat = (float*)(ws + base + 48 * MiB + 1536 * 1024);

  prep_x_kernel<<<8192, 256, 0, stream>>>(e, x16);
  cvt_w_kernel<<<3072, 256, 0, stream>>>(Wq, Wk, Wv, bq, bk, bv, wcat, bcat);

  // fused QKV: M=16384 N=1536 K=512; epilogue routes q/k plain, v transposed
  gemm3<128, _Float16, 1><<<dim3(12, 128, 1), 256, 0, stream>>>(
      x16, wcat, bcat, (_Float16*)nullptr, 512, 512, 0, 512, 0, 0, 0, q16, k16, vt, 0);

  if (big) {
    // S = q k^T batched: M=N=2048 K=512, f16 out
    gemm3<128, _Float16, 0><<<dim3(16, 16, 8), 256, 0, stream>>>(
        q16, k16, nullptr, S, 512, 512, 2048, 512,
        1048576LL, 1048576LL, 4194304LL, nullptr, nullptr, nullptr, 0);
    softmax_kernel<<<4096, 256, 0, stream>>>(S);
    // out = P v: BM=64, 1D grid 1024 with XCD decode; GY = 2048/64 = 32
    gemm3<64, float, 2><<<dim3(1024, 1, 1), 256, 0, stream>>>(
        S, vt, nullptr, out, 2048, 16384, 512, 2048,
        4194304LL, 2048LL, 1048576LL, nullptr, nullptr, nullptr, 32);
  } else {
    for (int b = 0; b < 8; b++) {
      gemm3<128, _Float16, 0><<<dim3(16, 16, 1), 256, 0, stream>>>(
          q16 + (long long)b * 1048576, k16 + (long long)b * 1048576, nullptr, S,
          512, 512, 2048, 512, 0, 0, 0, nullptr, nullptr, nullptr, 0);
      softmax_kernel<<<512, 256, 0, stream>>>(S);
      gemm3<64, float, 2><<<dim3(128, 1, 1), 256, 0, stream>>>(
          S, vt + (long long)b * 2048, nullptr, out + (long long)b * 1048576,
          2048, 16384, 512, 2048, 0, 0, 0, nullptr, nullptr, nullptr, 32);
    }
  }
}